// Round 1
// baseline (1444.885 us; speedup 1.0000x reference)
//
#include <hip/hip_runtime.h>

#define KDIM   41024
#define NCOLS  256
#define BATCH  4096
#define ROWS   8192
#define KSTEPS 641      // 41024 / 64

typedef _Float16 half8  __attribute__((ext_vector_type(8)));
typedef float    floatx4 __attribute__((ext_vector_type(4)));

__device__ __forceinline__ void async_load16(const void* g, void* l) {
    __builtin_amdgcn_global_load_lds(
        (const __attribute__((address_space(1))) void*)g,
        (__attribute__((address_space(3))) void*)l, 16, 0, 0);
}

__device__ __forceinline__ float clamp01(float x) { return fminf(fmaxf(x, 0.f), 1.f); }

// ---------------- W0 fp32 -> fp16 (layout preserved: [256][41024], i.e. B^T) ----
__global__ void cvt_w0_kernel(const float* __restrict__ w0, _Float16* __restrict__ w0h, int n4) {
    int i = blockIdx.x * blockDim.x + threadIdx.x;
    int stride = gridDim.x * blockDim.x;
    for (; i < n4; i += stride) {
        float4 v = reinterpret_cast<const float4*>(w0)[i];
        union { _Float16 h[4]; uint2 u; } o;
        o.h[0] = (_Float16)v.x; o.h[1] = (_Float16)v.y;
        o.h[2] = (_Float16)v.z; o.h[3] = (_Float16)v.w;
        reinterpret_cast<uint2*>(w0h)[i] = o.u;
    }
}

// ---------------- main GEMM: [8192 x 41024] @ W0^T -> partials[c][8192][256] ----
// tile 64 rows x 256 cols, BK=64, 256 threads = 4 waves (each 64x64, 4x4 frags of 16x16x32 f16)
__global__ __launch_bounds__(256, 3)
void gemm_kernel(const float* __restrict__ wf, const float* __restrict__ bf,
                 const _Float16* __restrict__ w0h, float* __restrict__ partials)
{
    __shared__ __align__(16) _Float16 Albuf[64 * 64];    // 8 KB  [row][slot^ (row&7)]
    __shared__ __align__(16) _Float16 Blbuf[NCOLS * 64]; // 32 KB [n][slot ^ (n&7)]

    const int tid  = threadIdx.x;
    const int lane = tid & 63;
    const int w    = tid >> 6;

    const int rb = blockIdx.x;   // 0..127 row-block (64 rows each); <64 white, >=64 black
    const int c  = blockIdx.y;   // k-chunk
    const int kc = gridDim.y;

    const int base = KSTEPS / kc;
    const int rem  = KSTEPS % kc;
    const int s0   = c * base + min(c, rem);
    const int ns   = base + (c < rem ? 1 : 0);

    const float* feat = (rb < 64) ? (wf + (size_t)(rb * 64) * KDIM)
                                  : (bf + (size_t)((rb - 64) * 64) * KDIM);

    floatx4 acc[4][4];
#pragma unroll
    for (int i = 0; i < 4; ++i)
#pragma unroll
        for (int j = 0; j < 4; ++j) acc[i][j] = (floatx4){0.f, 0.f, 0.f, 0.f};

    for (int s = 0; s < ns; ++s) {
        const int k0 = (s0 + s) * 64;

        // --- B tile: 256 n-rows x 64 k, fp16, via async global->LDS (16B/lane) ---
#pragma unroll
        for (int i = 0; i < 8; ++i) {
            const int nl  = i * 32 + (tid >> 3);
            const int sp  = tid & 7;
            const int ksl = sp ^ (nl & 7);              // XOR swizzle
            const _Float16* g = w0h + (size_t)nl * KDIM + k0 + ksl * 8;
            async_load16((const void*)g, (void*)(Blbuf + i * 2048 + tid * 8));
        }

        // --- A tile: 64 rows x 64 k, fp32 -> fp16 in-register, ds_write_b128 ---
#pragma unroll
        for (int u = 0; u < 2; ++u) {
            const int unit = tid + u * 256;
            const int row  = unit >> 3;
            const int sp   = unit & 7;
            const int ksl  = sp ^ (row & 7);
            const float4* gp = reinterpret_cast<const float4*>(feat + (size_t)row * KDIM + k0 + ksl * 8);
            float4 v0 = gp[0];
            float4 v1 = gp[1];
            half8 h;
            h[0] = (_Float16)v0.x; h[1] = (_Float16)v0.y; h[2] = (_Float16)v0.z; h[3] = (_Float16)v0.w;
            h[4] = (_Float16)v1.x; h[5] = (_Float16)v1.y; h[6] = (_Float16)v1.z; h[7] = (_Float16)v1.w;
            *reinterpret_cast<half8*>(&Albuf[row * 64 + sp * 8]) = h;
        }

        __syncthreads();

        // --- MFMA over the 64-deep K tile (two kk halves of 32) ---
#pragma unroll
        for (int kk = 0; kk < 2; ++kk) {
            const int lsl = kk * 4 + (lane >> 4);       // logical 8-elem k-slot
            half8 af[4], bfr[4];
#pragma unroll
            for (int mi = 0; mi < 4; ++mi) {
                const int row  = mi * 16 + (lane & 15);
                const int phys = lsl ^ (row & 7);
                af[mi] = *reinterpret_cast<const half8*>(&Albuf[row * 64 + phys * 8]);
            }
#pragma unroll
            for (int ni = 0; ni < 4; ++ni) {
                const int n    = w * 64 + ni * 16 + (lane & 15);
                const int phys = lsl ^ (n & 7);
                bfr[ni] = *reinterpret_cast<const half8*>(&Blbuf[n * 64 + phys * 8]);
            }
#pragma unroll
            for (int mi = 0; mi < 4; ++mi)
#pragma unroll
                for (int ni = 0; ni < 4; ++ni)
                    acc[mi][ni] = __builtin_amdgcn_mfma_f32_16x16x32_f16(af[mi], bfr[ni], acc[mi][ni], 0, 0, 0);
        }

        __syncthreads();
    }

    // --- epilogue: C/D layout col = lane&15, row = (lane>>4)*4 + reg ---
    const size_t pbase = ((size_t)c * ROWS + (size_t)rb * 64) * NCOLS;
    const int q    = lane >> 4;
    const int col0 = lane & 15;
#pragma unroll
    for (int mi = 0; mi < 4; ++mi)
#pragma unroll
        for (int ni = 0; ni < 4; ++ni)
#pragma unroll
            for (int r = 0; r < 4; ++r) {
                const int row = mi * 16 + q * 4 + r;
                const int col = w * 64 + ni * 16 + col0;
                partials[pbase + (size_t)row * NCOLS + col] = acc[mi][ni][r];
            }
}

// ---------------- tail: reduce partials, blend, clip, 3 tiny layers ----------
__global__ __launch_bounds__(256)
void tail_kernel(const float* __restrict__ partials, int kc,
                 const float* __restrict__ stm,
                 const float* __restrict__ b0,
                 const float* __restrict__ W1, const float* __restrict__ b1,
                 const float* __restrict__ W2, const float* __restrict__ b2,
                 const float* __restrict__ W3, const float* __restrict__ b3,
                 float* __restrict__ out)
{
    const int lane = threadIdx.x & 63;
    const int wid  = blockIdx.x * (blockDim.x >> 6) + (threadIdx.x >> 6);
    const int nw   = gridDim.x * (blockDim.x >> 6);

    for (int s = wid; s < BATCH; s += nw) {
        const float stmv = stm[s];
        float a1[4], a2[4];
#pragma unroll
        for (int j = 0; j < 4; ++j) {
            const int m = lane + 64 * j;
            float ws = 0.f, bs = 0.f;
            for (int cc = 0; cc < kc; ++cc) {
                ws += partials[((size_t)cc * ROWS + s) * NCOLS + m];
                bs += partials[((size_t)cc * ROWS + BATCH + s) * NCOLS + m];
            }
            ws += b0[m]; bs += b0[m];
            a1[j] = clamp01(stmv * ws + (1.f - stmv) * bs);
            a2[j] = clamp01(stmv * bs + (1.f - stmv) * ws);
        }
        float l2[32];
#pragma unroll
        for (int jo = 0; jo < 32; ++jo) {
            float t = 0.f;
#pragma unroll
            for (int j = 0; j < 4; ++j) {
                const int m = lane + 64 * j;
                t += a1[j] * W1[jo * 512 + m] + a2[j] * W1[jo * 512 + 256 + m];
            }
#pragma unroll
            for (int off = 32; off; off >>= 1) t += __shfl_xor(t, off, 64);
            l2[jo] = clamp01(t + b1[jo]);
        }
        float l3[32];
#pragma unroll
        for (int jo = 0; jo < 32; ++jo) {
            float t = b2[jo];
#pragma unroll
            for (int i = 0; i < 32; ++i) t += l2[i] * W2[jo * 32 + i];
            l3[jo] = clamp01(t);
        }
        float o = b3[0];
#pragma unroll
        for (int i = 0; i < 32; ++i) o += l3[i] * W3[i];
        if (lane == 0) out[s] = o;
    }
}

extern "C" void kernel_launch(void* const* d_in, const int* in_sizes, int n_in,
                              void* d_out, int out_size, void* d_ws, size_t ws_size,
                              hipStream_t stream) {
    const float* wf  = (const float*)d_in[0];
    const float* bff = (const float*)d_in[1];
    const float* stm = (const float*)d_in[2];
    const float* W0  = (const float*)d_in[3];
    const float* b0  = (const float*)d_in[4];
    const float* W1  = (const float*)d_in[5];
    const float* b1  = (const float*)d_in[6];
    const float* W2  = (const float*)d_in[7];
    const float* b2  = (const float*)d_in[8];
    const float* W3  = (const float*)d_in[9];
    const float* b3  = (const float*)d_in[10];
    float* out = (float*)d_out;

    const size_t w0h_bytes = (size_t)NCOLS * KDIM * 2;      // 21,004,288
    _Float16* w0h   = (_Float16*)d_ws;
    float* partials = (float*)((char*)d_ws + w0h_bytes);

    // kc=4 gives 512 GEMM blocks (2/CU); fall back to kc=1 if ws is small.
    int kc = 4;
    if (ws_size < w0h_bytes + (size_t)kc * ROWS * NCOLS * 4) kc = 1;

    cvt_w0_kernel<<<256, 256, 0, stream>>>(W0, w0h, NCOLS * KDIM / 4);

    dim3 g(128, kc);
    gemm_kernel<<<g, 256, 0, stream>>>(wf, bff, w0h, partials);

    tail_kernel<<<256, 256, 0, stream>>>(partials, kc, stm, b0, W1, b1, W2, b2, W3, b3, out);
}